// Round 5
// baseline (554.763 us; speedup 1.0000x reference)
//
#include <hip/hip_runtime.h>
#include <hip/hip_bf16.h>
#include <math.h>

#define HDIM 128
#define BN_EPS 1e-5f
#define CHUNK 512
#define TM 64            // rows per layer-2 tile
#define LDA 132          // padded LDS row stride (floats)

// ---- helpers ----
__device__ __forceinline__ int eget(const void* ei, long long pos, int is64) {
    return is64 ? (int)((const long long*)ei)[pos] : ((const int*)ei)[pos];
}
__device__ __forceinline__ unsigned short f2bf(float f) {
    unsigned int u = __float_as_uint(f);
    u += 0x7fffu + ((u >> 16) & 1u);
    return (unsigned short)(u >> 16);
}

// Detect int64 vs int32 layout: int64 values < 2^31 have zero hi-words.
__global__ void k_detect(const int* ei32, int* flag) {
    if (threadIdx.x == 0) {
        int nz = 0;
        for (int k = 0; k < 64; ++k) nz += (ei32[2 * k + 1] != 0);
        *flag = (nz < 8) ? 1 : 0;   // 1 => int64
    }
}

__global__ void k_count(const void* ei, const int* flag, int* cnt, int E) {
    int e = blockIdx.x * blockDim.x + threadIdx.x;
    if (e < E) {
        int d = eget(ei, (long long)E + e, *flag);
        atomicAdd(&cnt[d], 1);
    }
}

__global__ void k_dis(const int* cnt, float* dis, int N) {
    int i = blockIdx.x * blockDim.x + threadIdx.x;
    if (i < N) dis[i] = rsqrtf((float)(cnt[i] + 1));
}

// ---- 3-kernel exclusive scan of cnt[N] -> rowptr[N+1] ----
__global__ void k_scan1(const int* cnt, int* bsum, int N) {
    __shared__ int s[256];
    int t = threadIdx.x;
    int i = blockIdx.x * CHUNK + t;
    int v = 0;
    if (i < N) v += cnt[i];
    if (i + 256 < N && t + 256 < CHUNK) v += cnt[i + 256];
    s[t] = v; __syncthreads();
    for (int o = 128; o > 0; o >>= 1) {
        if (t < o) s[t] += s[t + o];
        __syncthreads();
    }
    if (t == 0) bsum[blockIdx.x] = s[0];
}

__global__ void k_scan2(int* bsum, int nb) {
    __shared__ int s[512];
    int t = threadIdx.x;
    int carry = 0;
    for (int base = 0; base < nb; base += 512) {
        int i = base + t;
        int v = (i < nb) ? bsum[i] : 0;
        s[t] = v; __syncthreads();
        for (int o = 1; o < 512; o <<= 1) {
            int add = (t >= o) ? s[t - o] : 0;
            __syncthreads();
            s[t] += add;
            __syncthreads();
        }
        if (i < nb) bsum[i] = carry + s[t] - v;   // exclusive
        carry += s[511];
        __syncthreads();
    }
}

__global__ void k_scan3(const int* cnt, const int* bsum, int* rowptr, int N) {
    __shared__ int s[CHUNK];
    int t = threadIdx.x;
    int i = blockIdx.x * CHUNK + t;
    int v = (i < N) ? cnt[i] : 0;
    s[t] = v; __syncthreads();
    for (int o = 1; o < CHUNK; o <<= 1) {
        int add = (t >= o) ? s[t - o] : 0;
        __syncthreads();
        s[t] += add;
        __syncthreads();
    }
    if (i < N) rowptr[i] = bsum[blockIdx.x] + s[t] - v;
    if (i == N - 1) rowptr[N] = bsum[blockIdx.x] + s[t];
}

__global__ void k_fillcsr(const void* ei, const int* flag, const float* dis,
                          const int* rowptr, int* fill, int* esrc, float* enorm, int E) {
    int e = blockIdx.x * blockDim.x + threadIdx.x;
    if (e < E) {
        int is64 = *flag;
        int s = eget(ei, e, is64);
        int d = eget(ei, (long long)E + e, is64);
        int pos = rowptr[d] + atomicAdd(&fill[d], 1);
        esrc[pos] = s;
        enorm[pos] = dis[s] * dis[d];
    }
}

// pad x (N x 6) into xp (N x 8, zero tail) for aligned float4 gathers
__global__ void k_padx(const float* __restrict__ x, float* __restrict__ xp, int N) {
    int t = blockIdx.x * blockDim.x + threadIdx.x;
    if (t < N * 8) {
        int i = t >> 3, c = t & 7;
        xp[t] = (c < 6) ? x[i * 6 + c] : 0.f;
    }
}

// layer-1 aggregation of padded x (thread per node), unrolled edge loop
__global__ void k_gath_x(const float* __restrict__ xp, const int* __restrict__ rowptr,
                         const int* __restrict__ esrc, const float* __restrict__ enorm,
                         const float* __restrict__ dis, float* __restrict__ aggx, int N) {
    int i = blockIdx.x * blockDim.x + threadIdx.x;
    if (i >= N) return;
    float d = dis[i], d2 = d * d;
    float4 A = *(const float4*)&xp[i * 8];
    float2 B = *(const float2*)&xp[i * 8 + 4];
    float a0 = A.x * d2, a1 = A.y * d2, a2 = A.z * d2;
    float a3 = A.w * d2, a4 = B.x * d2, a5 = B.y * d2;
    int p = rowptr[i], pe = rowptr[i + 1];
    for (; p + 2 <= pe; p += 2) {
        int s0 = esrc[p], s1 = esrc[p + 1];
        float n0 = enorm[p], n1 = enorm[p + 1];
        float4 A0 = *(const float4*)&xp[s0 * 8];
        float2 B0 = *(const float2*)&xp[s0 * 8 + 4];
        float4 A1 = *(const float4*)&xp[s1 * 8];
        float2 B1 = *(const float2*)&xp[s1 * 8 + 4];
        a0 += A0.x * n0 + A1.x * n1; a1 += A0.y * n0 + A1.y * n1;
        a2 += A0.z * n0 + A1.z * n1; a3 += A0.w * n0 + A1.w * n1;
        a4 += B0.x * n0 + B1.x * n1; a5 += B0.y * n0 + B1.y * n1;
    }
    if (p < pe) {
        int s0 = esrc[p]; float n0 = enorm[p];
        float4 A0 = *(const float4*)&xp[s0 * 8];
        float2 B0 = *(const float2*)&xp[s0 * 8 + 4];
        a0 += A0.x * n0; a1 += A0.y * n0; a2 += A0.z * n0;
        a3 += A0.w * n0; a4 += B0.x * n0; a5 += B0.y * n0;
    }
    aggx[i * 6 + 0] = a0; aggx[i * 6 + 1] = a1; aggx[i * 6 + 2] = a2;
    aggx[i * 6 + 3] = a3; aggx[i * 6 + 4] = a4; aggx[i * 6 + 5] = a5;
}

// m1[i][j] = dot(aggx[i], W1[:,j]) + b1[j]  (K=6) -> bf16, fused f32 col sums
__global__ void k_gemm6(const float* __restrict__ aggx, const float* __restrict__ W1,
                        const float* __restrict__ b1, unsigned short* __restrict__ out,
                        float* __restrict__ S, int N) {
    __shared__ float w[6 * HDIM];
    __shared__ float bb[HDIM];
    __shared__ float sh1[256], sh2[256];
    for (int t = threadIdx.x; t < 6 * HDIM; t += blockDim.x) w[t] = W1[t];
    if (threadIdx.x < HDIM) bb[threadIdx.x] = b1[threadIdx.x];
    __syncthreads();
    int j = threadIdx.x & (HDIM - 1);
    int sub = threadIdx.x >> 7;
    float s1 = 0.f, s2 = 0.f;
    for (long long i = blockIdx.x * 2 + sub; i < N; i += (long long)gridDim.x * 2) {
        const float* r = &aggx[i * 6];
        float acc = bb[j];
        acc += r[0] * w[0 * HDIM + j];
        acc += r[1] * w[1 * HDIM + j];
        acc += r[2] * w[2 * HDIM + j];
        acc += r[3] * w[3 * HDIM + j];
        acc += r[4] * w[4 * HDIM + j];
        acc += r[5] * w[5 * HDIM + j];
        out[i * HDIM + j] = f2bf(acc);
        s1 += acc; s2 += acc * acc;
    }
    sh1[threadIdx.x] = s1; sh2[threadIdx.x] = s2;
    __syncthreads();
    if (threadIdx.x < HDIM) {
        atomicAdd(&S[j], sh1[j] + sh1[j + HDIM]);
        atomicAdd(&S[HDIM + j], sh2[j] + sh2[j + HDIM]);
    }
}

__global__ void k_bnparams(const float* S, const float* g, const float* be,
                           float invN, float* P) {
    int j = threadIdx.x;
    if (j < HDIM) {
        float mu = S[j] * invN;
        float var = S[HDIM + j] * invN - mu * mu;
        float a = g[j] * rsqrtf(var + BN_EPS);
        P[j] = a;
        P[HDIM + j] = be[j] - mu * a;
    }
}

// accumulate 8 cols: a[k] += relu(pa[k]*bf2f(u)[k] + pb[k]) * wgt
__device__ __forceinline__ void gacc(float* a, const float* pa, const float* pb,
                                     uint4 u, float wgt) {
    unsigned int uu[4] = {u.x, u.y, u.z, u.w};
    #pragma unroll
    for (int q = 0; q < 4; ++q) {
        float lo = __uint_as_float(uu[q] << 16);
        float hi = __uint_as_float(uu[q] & 0xffff0000u);
        a[2 * q]     += fmaxf(fmaf(pa[2 * q],     lo, pb[2 * q]),     0.f) * wgt;
        a[2 * q + 1] += fmaxf(fmaf(pa[2 * q + 1], hi, pb[2 * q + 1]), 0.f) * wgt;
    }
}

// ===== fused layer 2: gather(m1 bf16, BN1+ReLU on the fly) -> LDS tile ->
//       GEMM 128x128 (W2 from L2) -> out f32 + column-sum epilogue.
//       Persistent blocks with atomic tile ticket. =====
__global__ __launch_bounds__(512, 8)
void k_agg_gemm(const unsigned short* __restrict__ m1, const float* __restrict__ P1,
                const int* __restrict__ rowptr, const int* __restrict__ esrc,
                const float* __restrict__ enorm, const float* __restrict__ dis,
                const float* __restrict__ W, const float* __restrict__ b,
                float* __restrict__ out, float* __restrict__ S,
                int* __restrict__ ticket, int ntiles, int N) {
    __shared__ float At[TM * LDA];
    __shared__ int s_tile;
    const int tid = threadIdx.x;

    // gather-phase constants
    const int gl = tid & 15;
    const int gg = tid >> 4;                // 0..31
    const int c8 = gl * 8;
    float pa[8], pb[8];
    {
        float4 t0 = *(const float4*)&P1[c8];
        float4 t1 = *(const float4*)&P1[c8 + 4];
        float4 t2 = *(const float4*)&P1[HDIM + c8];
        float4 t3 = *(const float4*)&P1[HDIM + c8 + 4];
        pa[0] = t0.x; pa[1] = t0.y; pa[2] = t0.z; pa[3] = t0.w;
        pa[4] = t1.x; pa[5] = t1.y; pa[6] = t1.z; pa[7] = t1.w;
        pb[0] = t2.x; pb[1] = t2.y; pb[2] = t2.z; pb[3] = t2.w;
        pb[4] = t3.x; pb[5] = t3.y; pb[6] = t3.z; pb[7] = t3.w;
    }
    // GEMM-phase constants
    const int cg = tid & 31;
    const int rg = tid >> 5;                // 0..15
    const int c0 = cg * 4;
    const int r0 = rg * 4;
    const float4 bv = *(const float4*)&b[c0];

    for (;;) {
        if (tid == 0) s_tile = atomicAdd(ticket, 1);
        __syncthreads();
        const int tile = s_tile;
        if (tile >= ntiles) return;
        const long long i0 = (long long)tile * TM;

        // ---- gather phase ----
        for (int nn = gg; nn < TM; nn += 32) {
            long long i = i0 + nn;
            float a[8] = {0.f, 0.f, 0.f, 0.f, 0.f, 0.f, 0.f, 0.f};
            if (i < N) {
                float d = dis[i];
                uint4 us = *(const uint4*)&m1[i * HDIM + c8];
                gacc(a, pa, pb, us, d * d);
                int p = rowptr[i], pe = rowptr[i + 1];
                for (; p + 4 <= pe; p += 4) {
                    int s0 = esrc[p], s1 = esrc[p + 1], s2 = esrc[p + 2], s3 = esrc[p + 3];
                    float n0 = enorm[p], n1 = enorm[p + 1], n2 = enorm[p + 2], n3 = enorm[p + 3];
                    uint4 u0 = *(const uint4*)&m1[(long long)s0 * HDIM + c8];
                    uint4 u1 = *(const uint4*)&m1[(long long)s1 * HDIM + c8];
                    uint4 u2 = *(const uint4*)&m1[(long long)s2 * HDIM + c8];
                    uint4 u3 = *(const uint4*)&m1[(long long)s3 * HDIM + c8];
                    gacc(a, pa, pb, u0, n0); gacc(a, pa, pb, u1, n1);
                    gacc(a, pa, pb, u2, n2); gacc(a, pa, pb, u3, n3);
                }
                if (p + 2 <= pe) {
                    int s0 = esrc[p], s1 = esrc[p + 1];
                    float n0 = enorm[p], n1 = enorm[p + 1];
                    uint4 u0 = *(const uint4*)&m1[(long long)s0 * HDIM + c8];
                    uint4 u1 = *(const uint4*)&m1[(long long)s1 * HDIM + c8];
                    gacc(a, pa, pb, u0, n0); gacc(a, pa, pb, u1, n1);
                    p += 2;
                }
                if (p < pe) {
                    int s0 = esrc[p]; float n0 = enorm[p];
                    uint4 u0 = *(const uint4*)&m1[(long long)s0 * HDIM + c8];
                    gacc(a, pa, pb, u0, n0);
                }
            }
            *(float4*)&At[nn * LDA + c8]     = make_float4(a[0], a[1], a[2], a[3]);
            *(float4*)&At[nn * LDA + c8 + 4] = make_float4(a[4], a[5], a[6], a[7]);
        }
        __syncthreads();

        // ---- GEMM phase: 4x4 register block per thread ----
        float acc[4][4];
        #pragma unroll
        for (int rr = 0; rr < 4; ++rr) {
            acc[rr][0] = bv.x; acc[rr][1] = bv.y; acc[rr][2] = bv.z; acc[rr][3] = bv.w;
        }
        for (int k = 0; k < HDIM; k += 4) {
            const float4 w0 = *(const float4*)&W[(k + 0) * HDIM + c0];
            const float4 w1 = *(const float4*)&W[(k + 1) * HDIM + c0];
            const float4 w2 = *(const float4*)&W[(k + 2) * HDIM + c0];
            const float4 w3 = *(const float4*)&W[(k + 3) * HDIM + c0];
            #pragma unroll
            for (int rr = 0; rr < 4; ++rr) {
                const float4 av = *(const float4*)&At[(r0 + rr) * LDA + k];
                acc[rr][0] = fmaf(av.x, w0.x, acc[rr][0]);
                acc[rr][1] = fmaf(av.x, w0.y, acc[rr][1]);
                acc[rr][2] = fmaf(av.x, w0.z, acc[rr][2]);
                acc[rr][3] = fmaf(av.x, w0.w, acc[rr][3]);
                acc[rr][0] = fmaf(av.y, w1.x, acc[rr][0]);
                acc[rr][1] = fmaf(av.y, w1.y, acc[rr][1]);
                acc[rr][2] = fmaf(av.y, w1.z, acc[rr][2]);
                acc[rr][3] = fmaf(av.y, w1.w, acc[rr][3]);
                acc[rr][0] = fmaf(av.z, w2.x, acc[rr][0]);
                acc[rr][1] = fmaf(av.z, w2.y, acc[rr][1]);
                acc[rr][2] = fmaf(av.z, w2.z, acc[rr][2]);
                acc[rr][3] = fmaf(av.z, w2.w, acc[rr][3]);
                acc[rr][0] = fmaf(av.w, w3.x, acc[rr][0]);
                acc[rr][1] = fmaf(av.w, w3.y, acc[rr][1]);
                acc[rr][2] = fmaf(av.w, w3.z, acc[rr][2]);
                acc[rr][3] = fmaf(av.w, w3.w, acc[rr][3]);
            }
        }

        // store + per-thread column partials
        float cs1[4] = {0.f, 0.f, 0.f, 0.f};
        float cs2[4] = {0.f, 0.f, 0.f, 0.f};
        #pragma unroll
        for (int rr = 0; rr < 4; ++rr) {
            long long i = i0 + r0 + rr;
            if (i < N) {
                *(float4*)&out[i * HDIM + c0] =
                    make_float4(acc[rr][0], acc[rr][1], acc[rr][2], acc[rr][3]);
                #pragma unroll
                for (int cc = 0; cc < 4; ++cc) {
                    float v = acc[rr][cc];
                    cs1[cc] += v; cs2[cc] += v * v;
                }
            }
        }
        __syncthreads();        // At free; reuse as reduction scratch
        #pragma unroll
        for (int cc = 0; cc < 4; ++cc) {
            At[rg * HDIM + c0 + cc]        = cs1[cc];
            At[2048 + rg * HDIM + c0 + cc] = cs2[cc];
        }
        __syncthreads();
        if (tid < 256) {
            int j = tid & (HDIM - 1);
            int which = tid >> 7;
            const float* bp = &At[which * 2048 + j];
            float s = 0.f;
            #pragma unroll
            for (int g = 0; g < 16; ++g) s += bp[g * HDIM];
            atomicAdd(&S[which * HDIM + j], s);
        }
        __syncthreads();        // protect At/s_tile before next iteration
    }
}

// m3[i] = dot(relu(BN2(m2[i])), W3); 32 lanes x float4 per row
__global__ void k_gemv2(const float* __restrict__ A, const float* __restrict__ P,
                        const float* __restrict__ W3, float* __restrict__ m3, int N) {
    int l = threadIdx.x & 31;
    int row = blockIdx.x * 8 + (threadIdx.x >> 5);
    if (row < N) {
        int c4 = l * 4;
        float4 pa = *(const float4*)&P[c4];
        float4 pb = *(const float4*)&P[HDIM + c4];
        float4 w  = *(const float4*)&W3[c4];
        float4 v  = *(const float4*)&A[(long long)row * HDIM + c4];
        float s = fmaxf(fmaf(pa.x, v.x, pb.x), 0.f) * w.x
                + fmaxf(fmaf(pa.y, v.y, pb.y), 0.f) * w.y
                + fmaxf(fmaf(pa.z, v.z, pb.z), 0.f) * w.z
                + fmaxf(fmaf(pa.w, v.w, pb.w), 0.f) * w.w;
        for (int o = 16; o > 0; o >>= 1) s += __shfl_down(s, o, 32);
        if (l == 0) m3[row] = s;
    }
}

// layer-3 gather + bias + sigmoid
__global__ void k_gath_o(const float* __restrict__ m3, const int* __restrict__ rowptr,
                         const int* __restrict__ esrc, const float* __restrict__ enorm,
                         const float* __restrict__ dis, const float* __restrict__ b3,
                         float* __restrict__ out, int N) {
    int i = blockIdx.x * blockDim.x + threadIdx.x;
    if (i < N) {
        float d = dis[i];
        float acc = m3[i] * d * d;
        int p = rowptr[i], pe = rowptr[i + 1];
        for (; p + 4 <= pe; p += 4) {
            float v0 = m3[esrc[p]]     * enorm[p];
            float v1 = m3[esrc[p + 1]] * enorm[p + 1];
            float v2 = m3[esrc[p + 2]] * enorm[p + 2];
            float v3 = m3[esrc[p + 3]] * enorm[p + 3];
            acc += (v0 + v1) + (v2 + v3);
        }
        for (; p < pe; ++p)
            acc += m3[esrc[p]] * enorm[p];
        acc += b3[0];
        out[i] = 1.f / (1.f + expf(-acc));
    }
}

extern "C" void kernel_launch(void* const* d_in, const int* in_sizes, int n_in,
                              void* d_out, int out_size, void* d_ws, size_t ws_size,
                              hipStream_t stream) {
    const float* x  = (const float*)d_in[0];
    const void*  ei = d_in[1];
    const float* W1 = (const float*)d_in[2];
    const float* b1 = (const float*)d_in[3];
    const float* W2 = (const float*)d_in[4];
    const float* b2 = (const float*)d_in[5];
    const float* W3 = (const float*)d_in[6];
    const float* b3 = (const float*)d_in[7];
    const float* g1 = (const float*)d_in[8];
    const float* be1 = (const float*)d_in[9];
    const float* g2 = (const float*)d_in[10];
    const float* be2 = (const float*)d_in[11];

    const int N = in_sizes[0] / 6;
    const int E = in_sizes[1] / 2;
    const float invN = 1.0f / (float)N;

    // ---- workspace layout (float units, 16B-aligned chunks) ----
    float* ws = (float*)d_ws;
    long long off = 0;
    auto pad4 = [](long long v) { return (v + 3) & ~3LL; };
    int*   flag   = (int*)ws;                 off += 16;   // [0]=flag, [1]=ticket
    int*   ticket = (int*)ws + 1;
    float* dis    = ws + off;                 off = pad4(off + N);
    int*   cnt    = (int*)(ws + off);         off = pad4(off + N);
    int*   rowptr = (int*)(ws + off);         off = pad4(off + N + 16);
    int*   esrc   = (int*)(ws + off);         off = pad4(off + E);
    float* enorm  = ws + off;                 off = pad4(off + E);
    int*   bsum   = (int*)(ws + off);         off += 512;
    float* S1     = ws + off;                 off += 256;
    float* S2     = ws + off;                 off += 256;
    float* P1     = ws + off;                 off += 256;
    float* P2     = ws + off;                 off += 256;
    float* xp     = ws + off;                 off = pad4(off + (long long)8 * N);
    float* aggx   = ws + off;                 off = pad4(off + (long long)6 * N);
    float* m3     = ws + off;                 off = pad4(off + N);
    // m1 is N*HDIM bf16 = 64N floats (was wrongly 32N in round 4 -> Hb2 overlap)
    unsigned short* m1 = (unsigned short*)(ws + off); off = pad4(off + (long long)64 * N);
    float* Hb2    = ws + off;                 off += (long long)HDIM * N;

    const int T = 256;
    const int bN  = (N + T - 1) / T;
    const int bE  = (E + T - 1) / T;
    const int nchunk = (N + CHUNK - 1) / CHUNK;
    const int ntiles = (N + TM - 1) / TM;

    // ---- CSR build + norm ----
    hipMemsetAsync(flag, 0, 64, stream);                  // flag + ticket
    hipMemsetAsync(S1, 0, 512 * sizeof(float), stream);   // S1 + S2
    k_detect<<<1, 64, 0, stream>>>((const int*)ei, flag);
    hipMemsetAsync(cnt, 0, (size_t)N * sizeof(int), stream);
    k_count<<<bE, T, 0, stream>>>(ei, flag, cnt, E);
    k_dis<<<bN, T, 0, stream>>>(cnt, dis, N);
    k_scan1<<<nchunk, 256, 0, stream>>>(cnt, bsum, N);
    k_scan2<<<1, 512, 0, stream>>>(bsum, nchunk);
    k_scan3<<<nchunk, CHUNK, 0, stream>>>(cnt, bsum, rowptr, N);
    hipMemsetAsync(cnt, 0, (size_t)N * sizeof(int), stream);   // becomes fill
    k_fillcsr<<<bE, T, 0, stream>>>(ei, flag, dis, rowptr, cnt, esrc, enorm, E);

    // ---- layer 1: pad x -> gather -> GEMM 6->128 (bf16 out, +colsum) ----
    k_padx<<<(N * 8 + T - 1) / T, T, 0, stream>>>(x, xp, N);
    k_gath_x<<<bN, T, 0, stream>>>(xp, rowptr, esrc, enorm, dis, aggx, N);
    k_gemm6<<<512, T, 0, stream>>>(aggx, W1, b1, m1, S1, N);
    k_bnparams<<<1, 128, 0, stream>>>(S1, g1, be1, invN, P1);

    // ---- layer 2 fused: gather(BN1+ReLU, bf16) -> GEMM (+colsum) ----
    k_agg_gemm<<<1024, 512, 0, stream>>>(m1, P1, rowptr, esrc, enorm, dis,
                                         W2, b2, Hb2, S2, ticket, ntiles, N);
    k_bnparams<<<1, 128, 0, stream>>>(S2, g2, be2, invN, P2);

    // ---- layer 3: (BN2+ReLU fused) 128->1, gather scalars + sigmoid ----
    k_gemv2<<<(N + 7) / 8, T, 0, stream>>>(Hb2, P2, W3, m3, N);
    k_gath_o<<<bN, T, 0, stream>>>(m3, rowptr, esrc, enorm, dis, b3, (float*)d_out, N);
}

// Round 6
// 286.791 us; speedup vs baseline: 1.9344x; 1.9344x over previous
//
#include <hip/hip_runtime.h>
#include <hip/hip_bf16.h>
#include <math.h>

#define HDIM 128
#define BN_EPS 1e-5f
#define CHUNK 512
#define TM 64            // rows per layer-2 tile
#define LDA 132          // padded LDS row stride (floats)

// ---- helpers ----
__device__ __forceinline__ int eget(const void* ei, long long pos, int is64) {
    return is64 ? (int)((const long long*)ei)[pos] : ((const int*)ei)[pos];
}
__device__ __forceinline__ unsigned short f2bf(float f) {
    unsigned int u = __float_as_uint(f);
    u += 0x7fffu + ((u >> 16) & 1u);
    return (unsigned short)(u >> 16);
}
__device__ __forceinline__ float bflo(unsigned int u) {
    return __uint_as_float(u << 16);
}
__device__ __forceinline__ float bfhi(unsigned int u) {
    return __uint_as_float(u & 0xffff0000u);
}

// Detect int64 vs int32 layout: int64 values < 2^31 have zero hi-words.
__global__ void k_detect(const int* ei32, int* flag) {
    if (threadIdx.x == 0) {
        int nz = 0;
        for (int k = 0; k < 64; ++k) nz += (ei32[2 * k + 1] != 0);
        *flag = (nz < 8) ? 1 : 0;   // 1 => int64
    }
}

__global__ void k_count(const void* ei, const int* flag, int* cnt, int E) {
    int e = blockIdx.x * blockDim.x + threadIdx.x;
    if (e < E) {
        int d = eget(ei, (long long)E + e, *flag);
        atomicAdd(&cnt[d], 1);
    }
}

__global__ void k_dis(const int* cnt, float* dis, int N) {
    int i = blockIdx.x * blockDim.x + threadIdx.x;
    if (i < N) dis[i] = rsqrtf((float)(cnt[i] + 1));
}

// ---- 3-kernel exclusive scan of cnt[N] -> rowptr[N+1] ----
__global__ void k_scan1(const int* cnt, int* bsum, int N) {
    __shared__ int s[256];
    int t = threadIdx.x;
    int i = blockIdx.x * CHUNK + t;
    int v = 0;
    if (i < N) v += cnt[i];
    if (i + 256 < N && t + 256 < CHUNK) v += cnt[i + 256];
    s[t] = v; __syncthreads();
    for (int o = 128; o > 0; o >>= 1) {
        if (t < o) s[t] += s[t + o];
        __syncthreads();
    }
    if (t == 0) bsum[blockIdx.x] = s[0];
}

__global__ void k_scan2(int* bsum, int nb) {
    __shared__ int s[512];
    int t = threadIdx.x;
    int carry = 0;
    for (int base = 0; base < nb; base += 512) {
        int i = base + t;
        int v = (i < nb) ? bsum[i] : 0;
        s[t] = v; __syncthreads();
        for (int o = 1; o < 512; o <<= 1) {
            int add = (t >= o) ? s[t - o] : 0;
            __syncthreads();
            s[t] += add;
            __syncthreads();
        }
        if (i < nb) bsum[i] = carry + s[t] - v;   // exclusive
        carry += s[511];
        __syncthreads();
    }
}

__global__ void k_scan3(const int* cnt, const int* bsum, int* rowptr, int N) {
    __shared__ int s[CHUNK];
    int t = threadIdx.x;
    int i = blockIdx.x * CHUNK + t;
    int v = (i < N) ? cnt[i] : 0;
    s[t] = v; __syncthreads();
    for (int o = 1; o < CHUNK; o <<= 1) {
        int add = (t >= o) ? s[t - o] : 0;
        __syncthreads();
        s[t] += add;
        __syncthreads();
    }
    if (i < N) rowptr[i] = bsum[blockIdx.x] + s[t] - v;
    if (i == N - 1) rowptr[N] = bsum[blockIdx.x] + s[t];
}

__global__ void k_fillcsr(const void* ei, const int* flag, const float* dis,
                          const int* rowptr, int* fill, int* esrc, float* enorm, int E) {
    int e = blockIdx.x * blockDim.x + threadIdx.x;
    if (e < E) {
        int is64 = *flag;
        int s = eget(ei, e, is64);
        int d = eget(ei, (long long)E + e, is64);
        int pos = rowptr[d] + atomicAdd(&fill[d], 1);
        esrc[pos] = s;
        enorm[pos] = dis[s] * dis[d];
    }
}

// pad x (N x 6) into xp (N x 8, zero tail) for aligned float4 gathers
__global__ void k_padx(const float* __restrict__ x, float* __restrict__ xp, int N) {
    int t = blockIdx.x * blockDim.x + threadIdx.x;
    if (t < N * 8) {
        int i = t >> 3, c = t & 7;
        xp[t] = (c < 6) ? x[i * 6 + c] : 0.f;
    }
}

// layer-1 aggregation of padded x (thread per node), unrolled edge loop
__global__ void k_gath_x(const float* __restrict__ xp, const int* __restrict__ rowptr,
                         const int* __restrict__ esrc, const float* __restrict__ enorm,
                         const float* __restrict__ dis, float* __restrict__ aggx, int N) {
    int i = blockIdx.x * blockDim.x + threadIdx.x;
    if (i >= N) return;
    float d = dis[i], d2 = d * d;
    float4 A = *(const float4*)&xp[i * 8];
    float2 B = *(const float2*)&xp[i * 8 + 4];
    float a0 = A.x * d2, a1 = A.y * d2, a2 = A.z * d2;
    float a3 = A.w * d2, a4 = B.x * d2, a5 = B.y * d2;
    int p = rowptr[i], pe = rowptr[i + 1];
    for (; p + 2 <= pe; p += 2) {
        int s0 = esrc[p], s1 = esrc[p + 1];
        float n0 = enorm[p], n1 = enorm[p + 1];
        float4 A0 = *(const float4*)&xp[s0 * 8];
        float2 B0 = *(const float2*)&xp[s0 * 8 + 4];
        float4 A1 = *(const float4*)&xp[s1 * 8];
        float2 B1 = *(const float2*)&xp[s1 * 8 + 4];
        a0 += A0.x * n0 + A1.x * n1; a1 += A0.y * n0 + A1.y * n1;
        a2 += A0.z * n0 + A1.z * n1; a3 += A0.w * n0 + A1.w * n1;
        a4 += B0.x * n0 + B1.x * n1; a5 += B0.y * n0 + B1.y * n1;
    }
    if (p < pe) {
        int s0 = esrc[p]; float n0 = enorm[p];
        float4 A0 = *(const float4*)&xp[s0 * 8];
        float2 B0 = *(const float2*)&xp[s0 * 8 + 4];
        a0 += A0.x * n0; a1 += A0.y * n0; a2 += A0.z * n0;
        a3 += A0.w * n0; a4 += B0.x * n0; a5 += B0.y * n0;
    }
    aggx[i * 6 + 0] = a0; aggx[i * 6 + 1] = a1; aggx[i * 6 + 2] = a2;
    aggx[i * 6 + 3] = a3; aggx[i * 6 + 4] = a4; aggx[i * 6 + 5] = a5;
}

// m1[i][j] = dot(aggx[i], W1[:,j]) + b1[j]  (K=6) -> bf16, fused f32 col sums
__global__ void k_gemm6(const float* __restrict__ aggx, const float* __restrict__ W1,
                        const float* __restrict__ b1, unsigned short* __restrict__ out,
                        float* __restrict__ S, int N) {
    __shared__ float w[6 * HDIM];
    __shared__ float bb[HDIM];
    __shared__ float sh1[256], sh2[256];
    for (int t = threadIdx.x; t < 6 * HDIM; t += blockDim.x) w[t] = W1[t];
    if (threadIdx.x < HDIM) bb[threadIdx.x] = b1[threadIdx.x];
    __syncthreads();
    int j = threadIdx.x & (HDIM - 1);
    int sub = threadIdx.x >> 7;
    float s1 = 0.f, s2 = 0.f;
    for (long long i = blockIdx.x * 2 + sub; i < N; i += (long long)gridDim.x * 2) {
        const float* r = &aggx[i * 6];
        float acc = bb[j];
        acc += r[0] * w[0 * HDIM + j];
        acc += r[1] * w[1 * HDIM + j];
        acc += r[2] * w[2 * HDIM + j];
        acc += r[3] * w[3 * HDIM + j];
        acc += r[4] * w[4 * HDIM + j];
        acc += r[5] * w[5 * HDIM + j];
        out[i * HDIM + j] = f2bf(acc);
        s1 += acc; s2 += acc * acc;
    }
    sh1[threadIdx.x] = s1; sh2[threadIdx.x] = s2;
    __syncthreads();
    if (threadIdx.x < HDIM) {
        atomicAdd(&S[j], sh1[j] + sh1[j + HDIM]);
        atomicAdd(&S[HDIM + j], sh2[j] + sh2[j + HDIM]);
    }
}

__global__ void k_bnparams(const float* S, const float* g, const float* be,
                           float invN, float* P) {
    int j = threadIdx.x;
    if (j < HDIM) {
        float mu = S[j] * invN;
        float var = S[HDIM + j] * invN - mu * mu;
        float a = g[j] * rsqrtf(var + BN_EPS);
        P[j] = a;
        P[HDIM + j] = be[j] - mu * a;
    }
}

// ===== fused layer 2: gather(m1 bf16, BN1+ReLU on the fly) -> LDS tile ->
//       GEMM 128x128 (W2 from L2) -> out f32 + column-sum epilogue.
//       Persistent blocks with atomic tile ticket.
//       Gather uses ONLY named scalars (round-5 array version spilled). =====
__global__ __launch_bounds__(512, 6)
void k_agg_gemm(const unsigned short* __restrict__ m1, const float* __restrict__ P1,
                const int* __restrict__ rowptr, const int* __restrict__ esrc,
                const float* __restrict__ enorm, const float* __restrict__ dis,
                const float* __restrict__ W, const float* __restrict__ b,
                float* __restrict__ out, float* __restrict__ S,
                int* __restrict__ ticket, int ntiles, int N) {
    __shared__ float At[TM * LDA];
    __shared__ int s_tile;
    const int tid = threadIdx.x;

    // gather-phase constants: 32 lanes x 4 cols (c4), 16 node-groups
    const int gl = tid & 31;
    const int gq = tid >> 5;                // 0..15
    const int c4 = gl * 4;
    const float4 pa = *(const float4*)&P1[c4];
    const float4 pb = *(const float4*)&P1[HDIM + c4];

    // GEMM-phase constants
    const int cg = tid & 31;
    const int rg = tid >> 5;                // 0..15
    const int c0 = cg * 4;
    const int r0 = rg * 4;
    const float4 bv = *(const float4*)&b[c0];

    for (;;) {
        if (tid == 0) s_tile = atomicAdd(ticket, 1);
        __syncthreads();
        const int tile = s_tile;
        if (tile >= ntiles) return;
        const long long i0 = (long long)tile * TM;

        // ---- gather phase ----
        for (int nn = gq; nn < TM; nn += 16) {
            long long i = i0 + nn;
            float a0 = 0.f, a1 = 0.f, a2 = 0.f, a3 = 0.f;
            if (i < N) {
                float d = dis[i], d2 = d * d;
                uint2 us = *(const uint2*)&m1[i * HDIM + c4];
                a0 = fmaxf(fmaf(pa.x, bflo(us.x), pb.x), 0.f) * d2;
                a1 = fmaxf(fmaf(pa.y, bfhi(us.x), pb.y), 0.f) * d2;
                a2 = fmaxf(fmaf(pa.z, bflo(us.y), pb.z), 0.f) * d2;
                a3 = fmaxf(fmaf(pa.w, bfhi(us.y), pb.w), 0.f) * d2;
                int p = rowptr[i], pe = rowptr[i + 1];
                for (; p + 2 <= pe; p += 2) {
                    int sA = esrc[p], sB = esrc[p + 1];
                    float nA = enorm[p], nB = enorm[p + 1];
                    uint2 uA = *(const uint2*)&m1[(long long)sA * HDIM + c4];
                    uint2 uB = *(const uint2*)&m1[(long long)sB * HDIM + c4];
                    a0 += fmaxf(fmaf(pa.x, bflo(uA.x), pb.x), 0.f) * nA
                        + fmaxf(fmaf(pa.x, bflo(uB.x), pb.x), 0.f) * nB;
                    a1 += fmaxf(fmaf(pa.y, bfhi(uA.x), pb.y), 0.f) * nA
                        + fmaxf(fmaf(pa.y, bfhi(uB.x), pb.y), 0.f) * nB;
                    a2 += fmaxf(fmaf(pa.z, bflo(uA.y), pb.z), 0.f) * nA
                        + fmaxf(fmaf(pa.z, bflo(uB.y), pb.z), 0.f) * nB;
                    a3 += fmaxf(fmaf(pa.w, bfhi(uA.y), pb.w), 0.f) * nA
                        + fmaxf(fmaf(pa.w, bfhi(uB.y), pb.w), 0.f) * nB;
                }
                if (p < pe) {
                    int sA = esrc[p]; float nA = enorm[p];
                    uint2 uA = *(const uint2*)&m1[(long long)sA * HDIM + c4];
                    a0 += fmaxf(fmaf(pa.x, bflo(uA.x), pb.x), 0.f) * nA;
                    a1 += fmaxf(fmaf(pa.y, bfhi(uA.x), pb.y), 0.f) * nA;
                    a2 += fmaxf(fmaf(pa.z, bflo(uA.y), pb.z), 0.f) * nA;
                    a3 += fmaxf(fmaf(pa.w, bfhi(uA.y), pb.w), 0.f) * nA;
                }
            }
            *(float4*)&At[nn * LDA + c4] = make_float4(a0, a1, a2, a3);
        }
        __syncthreads();

        // ---- GEMM phase: 4x4 register block per thread ----
        float acc[4][4];
        #pragma unroll
        for (int rr = 0; rr < 4; ++rr) {
            acc[rr][0] = bv.x; acc[rr][1] = bv.y; acc[rr][2] = bv.z; acc[rr][3] = bv.w;
        }
        for (int k = 0; k < HDIM; k += 4) {
            const float4 w0 = *(const float4*)&W[(k + 0) * HDIM + c0];
            const float4 w1 = *(const float4*)&W[(k + 1) * HDIM + c0];
            const float4 w2 = *(const float4*)&W[(k + 2) * HDIM + c0];
            const float4 w3 = *(const float4*)&W[(k + 3) * HDIM + c0];
            #pragma unroll
            for (int rr = 0; rr < 4; ++rr) {
                const float4 av = *(const float4*)&At[(r0 + rr) * LDA + k];
                acc[rr][0] = fmaf(av.x, w0.x, acc[rr][0]);
                acc[rr][1] = fmaf(av.x, w0.y, acc[rr][1]);
                acc[rr][2] = fmaf(av.x, w0.z, acc[rr][2]);
                acc[rr][3] = fmaf(av.x, w0.w, acc[rr][3]);
                acc[rr][0] = fmaf(av.y, w1.x, acc[rr][0]);
                acc[rr][1] = fmaf(av.y, w1.y, acc[rr][1]);
                acc[rr][2] = fmaf(av.y, w1.z, acc[rr][2]);
                acc[rr][3] = fmaf(av.y, w1.w, acc[rr][3]);
                acc[rr][0] = fmaf(av.z, w2.x, acc[rr][0]);
                acc[rr][1] = fmaf(av.z, w2.y, acc[rr][1]);
                acc[rr][2] = fmaf(av.z, w2.z, acc[rr][2]);
                acc[rr][3] = fmaf(av.z, w2.w, acc[rr][3]);
                acc[rr][0] = fmaf(av.w, w3.x, acc[rr][0]);
                acc[rr][1] = fmaf(av.w, w3.y, acc[rr][1]);
                acc[rr][2] = fmaf(av.w, w3.z, acc[rr][2]);
                acc[rr][3] = fmaf(av.w, w3.w, acc[rr][3]);
            }
        }

        // store + per-thread column partials
        float cs1[4] = {0.f, 0.f, 0.f, 0.f};
        float cs2[4] = {0.f, 0.f, 0.f, 0.f};
        #pragma unroll
        for (int rr = 0; rr < 4; ++rr) {
            long long i = i0 + r0 + rr;
            if (i < N) {
                *(float4*)&out[i * HDIM + c0] =
                    make_float4(acc[rr][0], acc[rr][1], acc[rr][2], acc[rr][3]);
                #pragma unroll
                for (int cc = 0; cc < 4; ++cc) {
                    float v = acc[rr][cc];
                    cs1[cc] += v; cs2[cc] += v * v;
                }
            }
        }
        __syncthreads();        // At free; reuse as reduction scratch
        #pragma unroll
        for (int cc = 0; cc < 4; ++cc) {
            At[rg * HDIM + c0 + cc]        = cs1[cc];
            At[2048 + rg * HDIM + c0 + cc] = cs2[cc];
        }
        __syncthreads();
        if (tid < 256) {
            int j = tid & (HDIM - 1);
            int which = tid >> 7;
            const float* bp = &At[which * 2048 + j];
            float s = 0.f;
            #pragma unroll
            for (int g = 0; g < 16; ++g) s += bp[g * HDIM];
            atomicAdd(&S[which * HDIM + j], s);
        }
        __syncthreads();        // protect At/s_tile before next iteration
    }
}

// m3[i] = dot(relu(BN2(m2[i])), W3); 32 lanes x float4 per row
__global__ void k_gemv2(const float* __restrict__ A, const float* __restrict__ P,
                        const float* __restrict__ W3, float* __restrict__ m3, int N) {
    int l = threadIdx.x & 31;
    int row = blockIdx.x * 8 + (threadIdx.x >> 5);
    if (row < N) {
        int c4 = l * 4;
        float4 pa = *(const float4*)&P[c4];
        float4 pb = *(const float4*)&P[HDIM + c4];
        float4 w  = *(const float4*)&W3[c4];
        float4 v  = *(const float4*)&A[(long long)row * HDIM + c4];
        float s = fmaxf(fmaf(pa.x, v.x, pb.x), 0.f) * w.x
                + fmaxf(fmaf(pa.y, v.y, pb.y), 0.f) * w.y
                + fmaxf(fmaf(pa.z, v.z, pb.z), 0.f) * w.z
                + fmaxf(fmaf(pa.w, v.w, pb.w), 0.f) * w.w;
        for (int o = 16; o > 0; o >>= 1) s += __shfl_down(s, o, 32);
        if (l == 0) m3[row] = s;
    }
}

// layer-3 gather + bias + sigmoid
__global__ void k_gath_o(const float* __restrict__ m3, const int* __restrict__ rowptr,
                         const int* __restrict__ esrc, const float* __restrict__ enorm,
                         const float* __restrict__ dis, const float* __restrict__ b3,
                         float* __restrict__ out, int N) {
    int i = blockIdx.x * blockDim.x + threadIdx.x;
    if (i < N) {
        float d = dis[i];
        float acc = m3[i] * d * d;
        int p = rowptr[i], pe = rowptr[i + 1];
        for (; p + 4 <= pe; p += 4) {
            float v0 = m3[esrc[p]]     * enorm[p];
            float v1 = m3[esrc[p + 1]] * enorm[p + 1];
            float v2 = m3[esrc[p + 2]] * enorm[p + 2];
            float v3 = m3[esrc[p + 3]] * enorm[p + 3];
            acc += (v0 + v1) + (v2 + v3);
        }
        for (; p < pe; ++p)
            acc += m3[esrc[p]] * enorm[p];
        acc += b3[0];
        out[i] = 1.f / (1.f + expf(-acc));
    }
}

extern "C" void kernel_launch(void* const* d_in, const int* in_sizes, int n_in,
                              void* d_out, int out_size, void* d_ws, size_t ws_size,
                              hipStream_t stream) {
    const float* x  = (const float*)d_in[0];
    const void*  ei = d_in[1];
    const float* W1 = (const float*)d_in[2];
    const float* b1 = (const float*)d_in[3];
    const float* W2 = (const float*)d_in[4];
    const float* b2 = (const float*)d_in[5];
    const float* W3 = (const float*)d_in[6];
    const float* b3 = (const float*)d_in[7];
    const float* g1 = (const float*)d_in[8];
    const float* be1 = (const float*)d_in[9];
    const float* g2 = (const float*)d_in[10];
    const float* be2 = (const float*)d_in[11];

    const int N = in_sizes[0] / 6;
    const int E = in_sizes[1] / 2;
    const float invN = 1.0f / (float)N;

    // ---- workspace layout (float units, 16B-aligned chunks) ----
    float* ws = (float*)d_ws;
    long long off = 0;
    auto pad4 = [](long long v) { return (v + 3) & ~3LL; };
    int*   flag   = (int*)ws;                 off += 16;   // [0]=flag, [1]=ticket
    int*   ticket = (int*)ws + 1;
    float* dis    = ws + off;                 off = pad4(off + N);
    int*   cnt    = (int*)(ws + off);         off = pad4(off + N);
    int*   rowptr = (int*)(ws + off);         off = pad4(off + N + 16);
    int*   esrc   = (int*)(ws + off);         off = pad4(off + E);
    float* enorm  = ws + off;                 off = pad4(off + E);
    int*   bsum   = (int*)(ws + off);         off += 512;
    float* S1     = ws + off;                 off += 256;
    float* S2     = ws + off;                 off += 256;
    float* P1     = ws + off;                 off += 256;
    float* P2     = ws + off;                 off += 256;
    float* xp     = ws + off;                 off = pad4(off + (long long)8 * N);
    float* aggx   = ws + off;                 off = pad4(off + (long long)6 * N);
    float* m3     = ws + off;                 off = pad4(off + N);
    // m1 is N*HDIM bf16 = 64N floats
    unsigned short* m1 = (unsigned short*)(ws + off); off = pad4(off + (long long)64 * N);
    float* Hb2    = ws + off;                 off += (long long)HDIM * N;

    const int T = 256;
    const int bN  = (N + T - 1) / T;
    const int bE  = (E + T - 1) / T;
    const int nchunk = (N + CHUNK - 1) / CHUNK;
    const int ntiles = (N + TM - 1) / TM;

    // ---- CSR build + norm ----
    hipMemsetAsync(flag, 0, 64, stream);                  // flag + ticket
    hipMemsetAsync(S1, 0, 512 * sizeof(float), stream);   // S1 + S2
    k_detect<<<1, 64, 0, stream>>>((const int*)ei, flag);
    hipMemsetAsync(cnt, 0, (size_t)N * sizeof(int), stream);
    k_count<<<bE, T, 0, stream>>>(ei, flag, cnt, E);
    k_dis<<<bN, T, 0, stream>>>(cnt, dis, N);
    k_scan1<<<nchunk, 256, 0, stream>>>(cnt, bsum, N);
    k_scan2<<<1, 512, 0, stream>>>(bsum, nchunk);
    k_scan3<<<nchunk, CHUNK, 0, stream>>>(cnt, bsum, rowptr, N);
    hipMemsetAsync(cnt, 0, (size_t)N * sizeof(int), stream);   // becomes fill
    k_fillcsr<<<bE, T, 0, stream>>>(ei, flag, dis, rowptr, cnt, esrc, enorm, E);

    // ---- layer 1: pad x -> gather -> GEMM 6->128 (bf16 out, +colsum) ----
    k_padx<<<(N * 8 + T - 1) / T, T, 0, stream>>>(x, xp, N);
    k_gath_x<<<bN, T, 0, stream>>>(xp, rowptr, esrc, enorm, dis, aggx, N);
    k_gemm6<<<512, T, 0, stream>>>(aggx, W1, b1, m1, S1, N);
    k_bnparams<<<1, 128, 0, stream>>>(S1, g1, be1, invN, P1);

    // ---- layer 2 fused: gather(BN1+ReLU, bf16) -> GEMM (+colsum) ----
    k_agg_gemm<<<1024, 512, 0, stream>>>(m1, P1, rowptr, esrc, enorm, dis,
                                         W2, b2, Hb2, S2, ticket, ntiles, N);
    k_bnparams<<<1, 128, 0, stream>>>(S2, g2, be2, invN, P2);

    // ---- layer 3: (BN2+ReLU fused) 128->1, gather scalars + sigmoid ----
    k_gemv2<<<(N + 7) / 8, T, 0, stream>>>(Hb2, P2, W3, m3, N);
    k_gath_o<<<bN, T, 0, stream>>>(m3, rowptr, esrc, enorm, dis, b3, (float*)d_out, N);
}

// Round 7
// 276.658 us; speedup vs baseline: 2.0052x; 1.0366x over previous
//
#include <hip/hip_runtime.h>
#include <hip/hip_bf16.h>
#include <math.h>

#define HDIM 128
#define BN_EPS 1e-5f
#define CHUNK 512
#define TM 64            // rows per layer-2 tile
#define LDA 132          // padded LDS row stride (floats)

// ---- helpers ----
__device__ __forceinline__ int eget(const void* ei, long long pos, int is64) {
    return is64 ? (int)((const long long*)ei)[pos] : ((const int*)ei)[pos];
}
__device__ __forceinline__ unsigned short f2bf(float f) {
    unsigned int u = __float_as_uint(f);
    u += 0x7fffu + ((u >> 16) & 1u);
    return (unsigned short)(u >> 16);
}
__device__ __forceinline__ unsigned int pack2bf(float lo, float hi) {
    return (unsigned int)f2bf(lo) | ((unsigned int)f2bf(hi) << 16);
}
__device__ __forceinline__ float bflo(unsigned int u) {
    return __uint_as_float(u << 16);
}
__device__ __forceinline__ float bfhi(unsigned int u) {
    return __uint_as_float(u & 0xffff0000u);
}

// Detect int64 vs int32 layout: int64 values < 2^31 have zero hi-words.
__global__ void k_detect(const int* ei32, int* flag) {
    if (threadIdx.x == 0) {
        int nz = 0;
        for (int k = 0; k < 64; ++k) nz += (ei32[2 * k + 1] != 0);
        *flag = (nz < 8) ? 1 : 0;   // 1 => int64
    }
}

__global__ void k_count(const void* ei, const int* flag, int* cnt, int E) {
    int e = blockIdx.x * blockDim.x + threadIdx.x;
    if (e < E) {
        int d = eget(ei, (long long)E + e, *flag);
        atomicAdd(&cnt[d], 1);
    }
}

__global__ void k_dis(const int* cnt, float* dis, int N) {
    int i = blockIdx.x * blockDim.x + threadIdx.x;
    if (i < N) dis[i] = rsqrtf((float)(cnt[i] + 1));
}

// ---- 3-kernel exclusive scan of cnt[N] -> rowptr[N+1] ----
__global__ void k_scan1(const int* cnt, int* bsum, int N) {
    __shared__ int s[256];
    int t = threadIdx.x;
    int i = blockIdx.x * CHUNK + t;
    int v = 0;
    if (i < N) v += cnt[i];
    if (i + 256 < N && t + 256 < CHUNK) v += cnt[i + 256];
    s[t] = v; __syncthreads();
    for (int o = 128; o > 0; o >>= 1) {
        if (t < o) s[t] += s[t + o];
        __syncthreads();
    }
    if (t == 0) bsum[blockIdx.x] = s[0];
}

__global__ void k_scan2(int* bsum, int nb) {
    __shared__ int s[512];
    int t = threadIdx.x;
    int carry = 0;
    for (int base = 0; base < nb; base += 512) {
        int i = base + t;
        int v = (i < nb) ? bsum[i] : 0;
        s[t] = v; __syncthreads();
        for (int o = 1; o < 512; o <<= 1) {
            int add = (t >= o) ? s[t - o] : 0;
            __syncthreads();
            s[t] += add;
            __syncthreads();
        }
        if (i < nb) bsum[i] = carry + s[t] - v;   // exclusive
        carry += s[511];
        __syncthreads();
    }
}

__global__ void k_scan3(const int* cnt, const int* bsum, int* rowptr, int N) {
    __shared__ int s[CHUNK];
    int t = threadIdx.x;
    int i = blockIdx.x * CHUNK + t;
    int v = (i < N) ? cnt[i] : 0;
    s[t] = v; __syncthreads();
    for (int o = 1; o < CHUNK; o <<= 1) {
        int add = (t >= o) ? s[t - o] : 0;
        __syncthreads();
        s[t] += add;
        __syncthreads();
    }
    if (i < N) rowptr[i] = bsum[blockIdx.x] + s[t] - v;
    if (i == N - 1) rowptr[N] = bsum[blockIdx.x] + s[t];
}

__global__ void k_fillcsr(const void* ei, const int* flag, const float* dis,
                          const int* rowptr, int* fill, int* esrc, float* enorm, int E) {
    int e = blockIdx.x * blockDim.x + threadIdx.x;
    if (e < E) {
        int is64 = *flag;
        int s = eget(ei, e, is64);
        int d = eget(ei, (long long)E + e, is64);
        int pos = rowptr[d] + atomicAdd(&fill[d], 1);
        esrc[pos] = s;
        enorm[pos] = dis[s] * dis[d];
    }
}

// pad x (N x 6) into xp (N x 8, zero tail) for aligned float4 gathers
__global__ void k_padx(const float* __restrict__ x, float* __restrict__ xp, int N) {
    int t = blockIdx.x * blockDim.x + threadIdx.x;
    if (t < N * 8) {
        int i = t >> 3, c = t & 7;
        xp[t] = (c < 6) ? x[i * 6 + c] : 0.f;
    }
}

// layer-1 aggregation of padded x (thread per node), edge loop unrolled x4
__global__ void k_gath_x(const float* __restrict__ xp, const int* __restrict__ rowptr,
                         const int* __restrict__ esrc, const float* __restrict__ enorm,
                         const float* __restrict__ dis, float* __restrict__ aggx, int N) {
    int i = blockIdx.x * blockDim.x + threadIdx.x;
    if (i >= N) return;
    float d = dis[i], d2 = d * d;
    float4 A = *(const float4*)&xp[i * 8];
    float2 B = *(const float2*)&xp[i * 8 + 4];
    float a0 = A.x * d2, a1 = A.y * d2, a2 = A.z * d2;
    float a3 = A.w * d2, a4 = B.x * d2, a5 = B.y * d2;
    int p = rowptr[i], pe = rowptr[i + 1];
    for (; p + 4 <= pe; p += 4) {
        int s0 = esrc[p], s1 = esrc[p + 1], s2 = esrc[p + 2], s3 = esrc[p + 3];
        float n0 = enorm[p], n1 = enorm[p + 1], n2 = enorm[p + 2], n3 = enorm[p + 3];
        float4 A0 = *(const float4*)&xp[s0 * 8];
        float2 B0 = *(const float2*)&xp[s0 * 8 + 4];
        float4 A1 = *(const float4*)&xp[s1 * 8];
        float2 B1 = *(const float2*)&xp[s1 * 8 + 4];
        float4 A2 = *(const float4*)&xp[s2 * 8];
        float2 B2 = *(const float2*)&xp[s2 * 8 + 4];
        float4 A3 = *(const float4*)&xp[s3 * 8];
        float2 B3 = *(const float2*)&xp[s3 * 8 + 4];
        a0 += (A0.x * n0 + A1.x * n1) + (A2.x * n2 + A3.x * n3);
        a1 += (A0.y * n0 + A1.y * n1) + (A2.y * n2 + A3.y * n3);
        a2 += (A0.z * n0 + A1.z * n1) + (A2.z * n2 + A3.z * n3);
        a3 += (A0.w * n0 + A1.w * n1) + (A2.w * n2 + A3.w * n3);
        a4 += (B0.x * n0 + B1.x * n1) + (B2.x * n2 + B3.x * n3);
        a5 += (B0.y * n0 + B1.y * n1) + (B2.y * n2 + B3.y * n3);
    }
    for (; p < pe; ++p) {
        int s0 = esrc[p]; float n0 = enorm[p];
        float4 A0 = *(const float4*)&xp[s0 * 8];
        float2 B0 = *(const float2*)&xp[s0 * 8 + 4];
        a0 += A0.x * n0; a1 += A0.y * n0; a2 += A0.z * n0;
        a3 += A0.w * n0; a4 += B0.x * n0; a5 += B0.y * n0;
    }
    aggx[i * 6 + 0] = a0; aggx[i * 6 + 1] = a1; aggx[i * 6 + 2] = a2;
    aggx[i * 6 + 3] = a3; aggx[i * 6 + 4] = a4; aggx[i * 6 + 5] = a5;
}

// m1[i][j] = dot(aggx[i], W1[:,j]) + b1[j]  (K=6) -> bf16, fused f32 col sums
__global__ void k_gemm6(const float* __restrict__ aggx, const float* __restrict__ W1,
                        const float* __restrict__ b1, unsigned short* __restrict__ out,
                        float* __restrict__ S, int N) {
    __shared__ float w[6 * HDIM];
    __shared__ float bb[HDIM];
    __shared__ float sh1[256], sh2[256];
    for (int t = threadIdx.x; t < 6 * HDIM; t += blockDim.x) w[t] = W1[t];
    if (threadIdx.x < HDIM) bb[threadIdx.x] = b1[threadIdx.x];
    __syncthreads();
    int j = threadIdx.x & (HDIM - 1);
    int sub = threadIdx.x >> 7;
    float s1 = 0.f, s2 = 0.f;
    for (long long i = blockIdx.x * 2 + sub; i < N; i += (long long)gridDim.x * 2) {
        const float* r = &aggx[i * 6];
        float acc = bb[j];
        acc += r[0] * w[0 * HDIM + j];
        acc += r[1] * w[1 * HDIM + j];
        acc += r[2] * w[2 * HDIM + j];
        acc += r[3] * w[3 * HDIM + j];
        acc += r[4] * w[4 * HDIM + j];
        acc += r[5] * w[5 * HDIM + j];
        out[i * HDIM + j] = f2bf(acc);
        s1 += acc; s2 += acc * acc;
    }
    sh1[threadIdx.x] = s1; sh2[threadIdx.x] = s2;
    __syncthreads();
    if (threadIdx.x < HDIM) {
        atomicAdd(&S[j], sh1[j] + sh1[j + HDIM]);
        atomicAdd(&S[HDIM + j], sh2[j] + sh2[j + HDIM]);
    }
}

// ===== fused layer 2: per-block BN1 params -> gather(m1 bf16, BN1+ReLU) ->
//       LDS tile -> GEMM 128x128 -> m2 bf16 + exact f32 column-sum epilogue.
//       Persistent blocks, atomic tile ticket. Named scalars only (no arrays
//       in the gather: round-5 array version went to scratch). =====
__global__ __launch_bounds__(512, 6)
void k_agg_gemm(const unsigned short* __restrict__ m1,
                const float* __restrict__ S1, const float* __restrict__ g1,
                const float* __restrict__ be1, float invN,
                const int* __restrict__ rowptr, const int* __restrict__ esrc,
                const float* __restrict__ enorm, const float* __restrict__ dis,
                const float* __restrict__ W, const float* __restrict__ b,
                unsigned short* __restrict__ out, float* __restrict__ S,
                int* __restrict__ ticket, int ntiles, int N) {
    __shared__ float At[TM * LDA];
    __shared__ float Pp[256];
    __shared__ int s_tile;
    const int tid = threadIdx.x;

    // per-block BN1 param compute (replaces k_bnparams launch)
    if (tid < HDIM) {
        float mu = S1[tid] * invN;
        float var = S1[HDIM + tid] * invN - mu * mu;
        float al = g1[tid] * rsqrtf(var + BN_EPS);
        Pp[tid] = al;
        Pp[HDIM + tid] = be1[tid] - mu * al;
    }
    __syncthreads();

    // gather-phase constants: 32 lanes x 4 cols, 16 node-groups
    const int gl = tid & 31;
    const int gq = tid >> 5;                // 0..15
    const int c4 = gl * 4;
    const float4 pa = *(const float4*)&Pp[c4];
    const float4 pb = *(const float4*)&Pp[HDIM + c4];

    // GEMM-phase constants
    const int cg = tid & 31;
    const int rg = tid >> 5;                // 0..15
    const int c0 = cg * 4;
    const int r0 = rg * 4;
    const float4 bv = *(const float4*)&b[c0];

    for (;;) {
        if (tid == 0) s_tile = atomicAdd(ticket, 1);
        __syncthreads();
        const int tile = s_tile;
        if (tile >= ntiles) return;
        const long long i0 = (long long)tile * TM;

        // ---- gather phase (edge loop unrolled x4: 4 row-loads in flight) ----
        for (int nn = gq; nn < TM; nn += 16) {
            long long i = i0 + nn;
            float a0 = 0.f, a1 = 0.f, a2 = 0.f, a3 = 0.f;
            if (i < N) {
                float d = dis[i], d2 = d * d;
                uint2 us = *(const uint2*)&m1[i * HDIM + c4];
                a0 = fmaxf(fmaf(pa.x, bflo(us.x), pb.x), 0.f) * d2;
                a1 = fmaxf(fmaf(pa.y, bfhi(us.x), pb.y), 0.f) * d2;
                a2 = fmaxf(fmaf(pa.z, bflo(us.y), pb.z), 0.f) * d2;
                a3 = fmaxf(fmaf(pa.w, bfhi(us.y), pb.w), 0.f) * d2;
                int p = rowptr[i], pe = rowptr[i + 1];
                for (; p + 4 <= pe; p += 4) {
                    int sA = esrc[p],     sB = esrc[p + 1];
                    int sC = esrc[p + 2], sD = esrc[p + 3];
                    float nA = enorm[p],     nB = enorm[p + 1];
                    float nC = enorm[p + 2], nD = enorm[p + 3];
                    uint2 uA = *(const uint2*)&m1[(long long)sA * HDIM + c4];
                    uint2 uB = *(const uint2*)&m1[(long long)sB * HDIM + c4];
                    uint2 uC = *(const uint2*)&m1[(long long)sC * HDIM + c4];
                    uint2 uD = *(const uint2*)&m1[(long long)sD * HDIM + c4];
                    a0 += (fmaxf(fmaf(pa.x, bflo(uA.x), pb.x), 0.f) * nA
                         + fmaxf(fmaf(pa.x, bflo(uB.x), pb.x), 0.f) * nB)
                        + (fmaxf(fmaf(pa.x, bflo(uC.x), pb.x), 0.f) * nC
                         + fmaxf(fmaf(pa.x, bflo(uD.x), pb.x), 0.f) * nD);
                    a1 += (fmaxf(fmaf(pa.y, bfhi(uA.x), pb.y), 0.f) * nA
                         + fmaxf(fmaf(pa.y, bfhi(uB.x), pb.y), 0.f) * nB)
                        + (fmaxf(fmaf(pa.y, bfhi(uC.x), pb.y), 0.f) * nC
                         + fmaxf(fmaf(pa.y, bfhi(uD.x), pb.y), 0.f) * nD);
                    a2 += (fmaxf(fmaf(pa.z, bflo(uA.y), pb.z), 0.f) * nA
                         + fmaxf(fmaf(pa.z, bflo(uB.y), pb.z), 0.f) * nB)
                        + (fmaxf(fmaf(pa.z, bflo(uC.y), pb.z), 0.f) * nC
                         + fmaxf(fmaf(pa.z, bflo(uD.y), pb.z), 0.f) * nD);
                    a3 += (fmaxf(fmaf(pa.w, bfhi(uA.y), pb.w), 0.f) * nA
                         + fmaxf(fmaf(pa.w, bfhi(uB.y), pb.w), 0.f) * nB)
                        + (fmaxf(fmaf(pa.w, bfhi(uC.y), pb.w), 0.f) * nC
                         + fmaxf(fmaf(pa.w, bfhi(uD.y), pb.w), 0.f) * nD);
                }
                if (p + 2 <= pe) {
                    int sA = esrc[p], sB = esrc[p + 1];
                    float nA = enorm[p], nB = enorm[p + 1];
                    uint2 uA = *(const uint2*)&m1[(long long)sA * HDIM + c4];
                    uint2 uB = *(const uint2*)&m1[(long long)sB * HDIM + c4];
                    a0 += fmaxf(fmaf(pa.x, bflo(uA.x), pb.x), 0.f) * nA
                        + fmaxf(fmaf(pa.x, bflo(uB.x), pb.x), 0.f) * nB;
                    a1 += fmaxf(fmaf(pa.y, bfhi(uA.x), pb.y), 0.f) * nA
                        + fmaxf(fmaf(pa.y, bfhi(uB.x), pb.y), 0.f) * nB;
                    a2 += fmaxf(fmaf(pa.z, bflo(uA.y), pb.z), 0.f) * nA
                        + fmaxf(fmaf(pa.z, bflo(uB.y), pb.z), 0.f) * nB;
                    a3 += fmaxf(fmaf(pa.w, bfhi(uA.y), pb.w), 0.f) * nA
                        + fmaxf(fmaf(pa.w, bfhi(uB.y), pb.w), 0.f) * nB;
                    p += 2;
                }
                if (p < pe) {
                    int sA = esrc[p]; float nA = enorm[p];
                    uint2 uA = *(const uint2*)&m1[(long long)sA * HDIM + c4];
                    a0 += fmaxf(fmaf(pa.x, bflo(uA.x), pb.x), 0.f) * nA;
                    a1 += fmaxf(fmaf(pa.y, bfhi(uA.x), pb.y), 0.f) * nA;
                    a2 += fmaxf(fmaf(pa.z, bflo(uA.y), pb.z), 0.f) * nA;
                    a3 += fmaxf(fmaf(pa.w, bfhi(uA.y), pb.w), 0.f) * nA;
                }
            }
            *(float4*)&At[nn * LDA + c4] = make_float4(a0, a1, a2, a3);
        }
        __syncthreads();

        // ---- GEMM phase: 4x4 register block per thread ----
        float acc[4][4];
        #pragma unroll
        for (int rr = 0; rr < 4; ++rr) {
            acc[rr][0] = bv.x; acc[rr][1] = bv.y; acc[rr][2] = bv.z; acc[rr][3] = bv.w;
        }
        for (int k = 0; k < HDIM; k += 4) {
            const float4 w0 = *(const float4*)&W[(k + 0) * HDIM + c0];
            const float4 w1 = *(const float4*)&W[(k + 1) * HDIM + c0];
            const float4 w2 = *(const float4*)&W[(k + 2) * HDIM + c0];
            const float4 w3 = *(const float4*)&W[(k + 3) * HDIM + c0];
            #pragma unroll
            for (int rr = 0; rr < 4; ++rr) {
                const float4 av = *(const float4*)&At[(r0 + rr) * LDA + k];
                acc[rr][0] = fmaf(av.x, w0.x, acc[rr][0]);
                acc[rr][1] = fmaf(av.x, w0.y, acc[rr][1]);
                acc[rr][2] = fmaf(av.x, w0.z, acc[rr][2]);
                acc[rr][3] = fmaf(av.x, w0.w, acc[rr][3]);
                acc[rr][0] = fmaf(av.y, w1.x, acc[rr][0]);
                acc[rr][1] = fmaf(av.y, w1.y, acc[rr][1]);
                acc[rr][2] = fmaf(av.y, w1.z, acc[rr][2]);
                acc[rr][3] = fmaf(av.y, w1.w, acc[rr][3]);
                acc[rr][0] = fmaf(av.z, w2.x, acc[rr][0]);
                acc[rr][1] = fmaf(av.z, w2.y, acc[rr][1]);
                acc[rr][2] = fmaf(av.z, w2.z, acc[rr][2]);
                acc[rr][3] = fmaf(av.z, w2.w, acc[rr][3]);
                acc[rr][0] = fmaf(av.w, w3.x, acc[rr][0]);
                acc[rr][1] = fmaf(av.w, w3.y, acc[rr][1]);
                acc[rr][2] = fmaf(av.w, w3.z, acc[rr][2]);
                acc[rr][3] = fmaf(av.w, w3.w, acc[rr][3]);
            }
        }

        // store m2 as bf16 + per-thread exact f32 column partials
        float cs1[4] = {0.f, 0.f, 0.f, 0.f};
        float cs2[4] = {0.f, 0.f, 0.f, 0.f};
        #pragma unroll
        for (int rr = 0; rr < 4; ++rr) {
            long long i = i0 + r0 + rr;
            if (i < N) {
                uint2 o;
                o.x = pack2bf(acc[rr][0], acc[rr][1]);
                o.y = pack2bf(acc[rr][2], acc[rr][3]);
                *(uint2*)&out[i * HDIM + c0] = o;
                #pragma unroll
                for (int cc = 0; cc < 4; ++cc) {
                    float v = acc[rr][cc];
                    cs1[cc] += v; cs2[cc] += v * v;
                }
            }
        }
        __syncthreads();        // At free; reuse as reduction scratch
        #pragma unroll
        for (int cc = 0; cc < 4; ++cc) {
            At[rg * HDIM + c0 + cc]        = cs1[cc];
            At[2048 + rg * HDIM + c0 + cc] = cs2[cc];
        }
        __syncthreads();
        if (tid < 256) {
            int j = tid & (HDIM - 1);
            int which = tid >> 7;
            const float* bp = &At[which * 2048 + j];
            float s = 0.f;
            #pragma unroll
            for (int g = 0; g < 16; ++g) s += bp[g * HDIM];
            atomicAdd(&S[which * HDIM + j], s);
        }
        __syncthreads();        // protect At/s_tile before next iteration
    }
}

// m3[i] = dot(relu(BN2(m2[i])), W3), m2 bf16; per-block BN2 params; persistent
__global__ void k_gemv2(const unsigned short* __restrict__ m2,
                        const float* __restrict__ S2, const float* __restrict__ g2,
                        const float* __restrict__ be2, float invN,
                        const float* __restrict__ W3, float* __restrict__ m3, int N) {
    __shared__ float Pp[256];
    int tid = threadIdx.x;
    if (tid < HDIM) {
        float mu = S2[tid] * invN;
        float var = S2[HDIM + tid] * invN - mu * mu;
        float al = g2[tid] * rsqrtf(var + BN_EPS);
        Pp[tid] = al;
        Pp[HDIM + tid] = be2[tid] - mu * al;
    }
    __syncthreads();
    int l = tid & 31;
    int c4 = l * 4;
    float4 pa = *(const float4*)&Pp[c4];
    float4 pb = *(const float4*)&Pp[HDIM + c4];
    float4 w  = *(const float4*)&W3[c4];
    for (long long row = blockIdx.x * 8 + (tid >> 5); row < N;
         row += (long long)gridDim.x * 8) {
        uint2 v = *(const uint2*)&m2[row * HDIM + c4];
        float s = fmaxf(fmaf(pa.x, bflo(v.x), pb.x), 0.f) * w.x
                + fmaxf(fmaf(pa.y, bfhi(v.x), pb.y), 0.f) * w.y
                + fmaxf(fmaf(pa.z, bflo(v.y), pb.z), 0.f) * w.z
                + fmaxf(fmaf(pa.w, bfhi(v.y), pb.w), 0.f) * w.w;
        for (int o = 16; o > 0; o >>= 1) s += __shfl_down(s, o, 32);
        if (l == 0) m3[row] = s;
    }
}

// layer-3 gather + bias + sigmoid
__global__ void k_gath_o(const float* __restrict__ m3, const int* __restrict__ rowptr,
                         const int* __restrict__ esrc, const float* __restrict__ enorm,
                         const float* __restrict__ dis, const float* __restrict__ b3,
                         float* __restrict__ out, int N) {
    int i = blockIdx.x * blockDim.x + threadIdx.x;
    if (i < N) {
        float d = dis[i];
        float acc = m3[i] * d * d;
        int p = rowptr[i], pe = rowptr[i + 1];
        for (; p + 4 <= pe; p += 4) {
            float v0 = m3[esrc[p]]     * enorm[p];
            float v1 = m3[esrc[p + 1]] * enorm[p + 1];
            float v2 = m3[esrc[p + 2]] * enorm[p + 2];
            float v3 = m3[esrc[p + 3]] * enorm[p + 3];
            acc += (v0 + v1) + (v2 + v3);
        }
        for (; p < pe; ++p)
            acc += m3[esrc[p]] * enorm[p];
        acc += b3[0];
        out[i] = 1.f / (1.f + expf(-acc));
    }
}

extern "C" void kernel_launch(void* const* d_in, const int* in_sizes, int n_in,
                              void* d_out, int out_size, void* d_ws, size_t ws_size,
                              hipStream_t stream) {
    const float* x  = (const float*)d_in[0];
    const void*  ei = d_in[1];
    const float* W1 = (const float*)d_in[2];
    const float* b1 = (const float*)d_in[3];
    const float* W2 = (const float*)d_in[4];
    const float* b2 = (const float*)d_in[5];
    const float* W3 = (const float*)d_in[6];
    const float* b3 = (const float*)d_in[7];
    const float* g1 = (const float*)d_in[8];
    const float* be1 = (const float*)d_in[9];
    const float* g2 = (const float*)d_in[10];
    const float* be2 = (const float*)d_in[11];

    const int N = in_sizes[0] / 6;
    const int E = in_sizes[1] / 2;
    const float invN = 1.0f / (float)N;

    // ---- workspace layout (float units, 16B-aligned chunks) ----
    float* ws = (float*)d_ws;
    long long off = 0;
    auto pad4 = [](long long v) { return (v + 3) & ~3LL; };
    int*   flag   = (int*)ws;                 off += 16;   // [0]=flag, [1]=ticket
    int*   ticket = (int*)ws + 1;
    float* dis    = ws + off;                 off = pad4(off + N);
    int*   cnt    = (int*)(ws + off);         off = pad4(off + N);
    int*   rowptr = (int*)(ws + off);         off = pad4(off + N + 16);
    int*   esrc   = (int*)(ws + off);         off = pad4(off + E);
    float* enorm  = ws + off;                 off = pad4(off + E);
    int*   bsum   = (int*)(ws + off);         off += 512;
    float* S1     = ws + off;                 off += 256;
    float* S2     = ws + off;                 off += 256;
    float* xp     = ws + off;                 off = pad4(off + (long long)8 * N);
    float* aggx   = ws + off;                 off = pad4(off + (long long)6 * N);
    float* m3     = ws + off;                 off = pad4(off + N);
    // m1, m2: N x 128 bf16 = 64N floats each
    unsigned short* m1 = (unsigned short*)(ws + off); off = pad4(off + (long long)64 * N);
    unsigned short* m2 = (unsigned short*)(ws + off); off = pad4(off + (long long)64 * N);

    const int T = 256;
    const int bN  = (N + T - 1) / T;
    const int bE  = (E + T - 1) / T;
    const int nchunk = (N + CHUNK - 1) / CHUNK;
    const int ntiles = (N + TM - 1) / TM;

    // ---- CSR build + norm ----
    hipMemsetAsync(flag, 0, 64, stream);                  // flag + ticket
    hipMemsetAsync(S1, 0, 512 * sizeof(float), stream);   // S1 + S2
    k_detect<<<1, 64, 0, stream>>>((const int*)ei, flag);
    hipMemsetAsync(cnt, 0, (size_t)N * sizeof(int), stream);
    k_count<<<bE, T, 0, stream>>>(ei, flag, cnt, E);
    k_dis<<<bN, T, 0, stream>>>(cnt, dis, N);
    k_scan1<<<nchunk, 256, 0, stream>>>(cnt, bsum, N);
    k_scan2<<<1, 512, 0, stream>>>(bsum, nchunk);
    k_scan3<<<nchunk, CHUNK, 0, stream>>>(cnt, bsum, rowptr, N);
    hipMemsetAsync(cnt, 0, (size_t)N * sizeof(int), stream);   // becomes fill
    k_fillcsr<<<bE, T, 0, stream>>>(ei, flag, dis, rowptr, cnt, esrc, enorm, E);

    // ---- layer 1: pad x -> gather -> GEMM 6->128 (bf16 out, +colsum) ----
    k_padx<<<(N * 8 + T - 1) / T, T, 0, stream>>>(x, xp, N);
    k_gath_x<<<bN, T, 0, stream>>>(xp, rowptr, esrc, enorm, dis, aggx, N);
    k_gemm6<<<512, T, 0, stream>>>(aggx, W1, b1, m1, S1, N);

    // ---- layer 2 fused: BN1 params in-kernel -> gather -> GEMM -> bf16 m2 ----
    k_agg_gemm<<<1024, 512, 0, stream>>>(m1, S1, g1, be1, invN,
                                         rowptr, esrc, enorm, dis,
                                         W2, b2, m2, S2, ticket, ntiles, N);

    // ---- layer 3: BN2 params in-kernel; 128->1; gather scalars + sigmoid ----
    k_gemv2<<<1024, T, 0, stream>>>(m2, S2, g2, be2, invN, W3, m3, N);
    k_gath_o<<<bN, T, 0, stream>>>(m3, rowptr, esrc, enorm, dis, b3, (float*)d_out, N);
}